// Round 10
// baseline (550.002 us; speedup 1.0000x reference)
//
#include <hip/hip_runtime.h>
#include <hip/hip_bf16.h>

typedef __hip_bfloat16 bf16;
typedef __attribute__((ext_vector_type(8))) short short8;   // 8 bf16 = 4 VGPRs
typedef __attribute__((ext_vector_type(4))) float f32x4;    // MFMA acc

__device__ __forceinline__ float b2f(bf16 x){ return __bfloat162float(x); }
__device__ __forceinline__ bf16  f2b(float x){ return __float2bfloat16(x); }
__device__ __forceinline__ float s2f(short s){ bf16 t = *(bf16*)&s; return b2f(t); }

// dual-dtype input load / output store (flag: 1 = fp32 storage, 0 = bf16)
__device__ __forceinline__ float ldin(const void* p, size_t i, int f32){
  return f32 ? ((const float*)p)[i] : b2f(((const bf16*)p)[i]);
}
__device__ __forceinline__ void stout(void* p, size_t i, float v, int f32){
  if(f32) ((float*)p)[i] = v; else ((bf16*)p)[i] = f2b(v);
}

constexpr int SP   = 32*32*32;   // 32768 spatial per (b,c)
constexpr int LTOK = SP;         // tokens per batch
constexpr int NC   = 512;        // scan chunks
constexpr int CLEN = LTOK / NC;  // 64
constexpr int NSEQ = 2*2*64*8;   // 2048 scan sequences (dir,b,d,n)
constexpr int SEG  = 16;         // scan2 hierarchy: 16 segments x 32 chunks
constexpr int SEGLEN = NC/SEG;   // 32

// ---------------------------------------------------------------- dtype detector
__global__ void k_detect(const void* conv_w, int* flag){
  if(threadIdx.x==0 && blockIdx.x==0){
    const bf16* p = (const bf16*)conv_w;
    int f = 0;
    for(int i=0;i<128;i++){
      float v = b2f(p[i]);
      if(!(v==v) || fabsf(v) > 1.0f) f = 1;   // bf16 weights are 0.05-scale
    }
    *flag = f;
  }
}

// ---------------------------------------------------------------- diagnostic fill
__global__ void k_fill(void* out, int n, const int* flag){
  const int f32 = *flag;
  int i = blockIdx.x*256 + threadIdx.x;
  if(i<n) stout(out, i, 12345.0f, f32);
}

// ---------------------------------------------------------------- weight re-layout: wt[tap][oc][ci]
__global__ void k_wprep(const void* __restrict__ cw, bf16* __restrict__ wt,
                        const int* __restrict__ flag){
  const int f32 = *flag;
  int t = blockIdx.x*256 + threadIdx.x;   // 110592 = 27*64*64
  if(t >= 27*64*64) return;
  int tap = t >> 12;          // /4096
  int oc  = (t >> 6) & 63;
  int ci  = t & 63;
  wt[t] = f2b(ldin(cw, ((size_t)(oc*64+ci))*27 + tap, f32));
}

// ---------------------------------------------------------------- in_proj as MFMA GEMM
__global__ __launch_bounds__(256) void k_inprojm(
    const void* __restrict__ in, const void* __restrict__ pw,
    bf16* __restrict__ xz, bf16* __restrict__ xin_t,
    const int* __restrict__ flag){
  const int f32 = *flag;
  __shared__ bf16 tok[128*72];   // [token][c], pitch 72
  __shared__ bf16 wl [128*72];   // [j][c],     pitch 72
  int tid = threadIdx.x;
  int b = blockIdx.x >> 8, tile = blockIdx.x & 255;
  int l0 = tile*128;

  for(int p=tid; p<1024; p+=256){          // weights: (j, c8)
    int j = p & 127, c8 = p >> 7;
    short8 v;
    #pragma unroll
    for(int k=0;k<8;k++){
      bf16 t = f2b(ldin(pw, j*64 + c8*8 + k, f32));
      v[k] = *(short*)&t;
    }
    *(short8*)(&wl[j*72 + c8*8]) = v;
  }
  for(int p=tid; p<1024; p+=256){          // tokens: (i, c8), coalesced over i
    int i = p & 127, c8 = p >> 7;
    short8 v;
    #pragma unroll
    for(int k=0;k<8;k++){
      bf16 t = f2b(ldin(in, ((size_t)(b*64 + c8*8 + k))*SP + l0 + i, f32));
      v[k] = *(short*)&t;
    }
    *(short8*)(&tok[i*72 + c8*8]) = v;
  }
  __syncthreads();

  int lane = tid & 63, wv = tid >> 6;
  int pn = lane & 15, quad = lane >> 4, kg8 = quad*8;
  f32x4 acc[2][8];
  #pragma unroll
  for(int mt=0;mt<2;mt++)
    #pragma unroll
    for(int nt=0;nt<8;nt++) acc[mt][nt]=(f32x4)(0.f);

  #pragma unroll
  for(int kq=0;kq<2;kq++){
    short8 a0 = *(const short8*)(&tok[(wv*32      + pn)*72 + kq*32 + kg8]);
    short8 a1 = *(const short8*)(&tok[(wv*32 + 16 + pn)*72 + kq*32 + kg8]);
    #pragma unroll
    for(int nt=0;nt<8;nt++){
      short8 bb = *(const short8*)(&wl[(nt*16+pn)*72 + kq*32 + kg8]);
      acc[0][nt] = __builtin_amdgcn_mfma_f32_16x16x32_bf16(a0,bb,acc[0][nt],0,0,0);
      acc[1][nt] = __builtin_amdgcn_mfma_f32_16x16x32_bf16(a1,bb,acc[1][nt],0,0,0);
    }
  }

  #pragma unroll
  for(int mt=0;mt<2;mt++){
    #pragma unroll
    for(int nt=0;nt<8;nt++){
      #pragma unroll
      for(int r=0;r<4;r++){
        int token = wv*32 + mt*16 + quad*4 + r;
        xz[((size_t)b*LTOK + l0 + token)*128 + nt*16 + pn] = f2b(acc[mt][nt][r]);
      }
    }
  }
  for(int p=tid; p<8192; p+=256){
    int i = p >> 6, c = p & 63;
    xin_t[((size_t)b*SP + l0 + i)*64 + c] = tok[i*72 + c];
  }
}

// ---------------------------------------------------------------- MFMA conv3d (both convs)
// R10 restructure for occupancy: 2 w-rows x 32 d per block (grid 1024),
// LDS 35.9 KB pitch-44 (2-way max conflicts vs pitch-40's 8-way),
// wave = (w-row, d-half), 4 acc tiles. 4 blocks/CU, 4 waves/SIMD.
__global__ __launch_bounds__(256, 4) void k_convm(
    const bf16* __restrict__ xin_t, const bf16* __restrict__ wt,
    const void* __restrict__ cb, const bf16* __restrict__ skip,
    bf16* __restrict__ out_bf, void* __restrict__ out_any,
    int mode, const int* __restrict__ flag){
  const int f32 = *flag;
  __shared__ bf16 xt[408*44];   // [ (hh*4+ww)*34 + dd ][ 44 ] = 35,904 B

  int tid  = threadIdx.x;
  int lane = tid & 63;
  int wv   = tid >> 6;
  int wr   = wv & 1;            // local w-row
  int dh   = wv >> 1;           // d-half
  int pn   = lane & 15;
  int quad = lane >> 4;
  int kg8  = quad * 8;
  int laneA = pn*64 + kg8;

  int blk = blockIdx.x;         // 1024 = 2b * 32h * 16wg
  int b  = blk >> 9;
  int h  = (blk >> 4) & 31;
  int w0 = (blk & 15) * 2;

  f32x4 acc[4];
  #pragma unroll
  for(int m=0;m<4;m++) acc[m]=(f32x4)(0.f);

  for(int cic=0; cic<64; cic+=32){
    if(cic) __syncthreads();
    if(cic==0){
      for(int i=tid; i<96; i+=256){        // zero d-halo rows (dd=0,33), 12 hw x 2 x 4q
        int q4 = i & 3; int rr = i >> 2;
        int dd = (rr & 1) ? 33 : 0; int hw = rr >> 1;
        *(short8*)(&xt[(hw*34 + dd)*44 + q4*8]) = (short8)(0);
      }
    }
    // stage 3h x 4w x 32d x 32ci: 1536 b128 transfers, 6 iters
    #pragma unroll
    for(int it=0; it<6; it++){
      int j = it*256 + tid;
      int q4  = j & 3;
      int row = j >> 2;          // 0..383
      int d   = row & 31;
      int hw  = row >> 5;        // 0..11
      int ww  = hw & 3, hh = hw >> 2;
      int hg = h + hh - 1, wg = w0 + ww - 1;
      short8 v = (short8)(0);
      if((unsigned)hg < 32u && (unsigned)wg < 32u)
        v = *(const short8*)(&xin_t[(((size_t)b*SP) + hg*1024 + wg*32 + d)*64 + cic + q4*8]);
      *(short8*)(&xt[((hh*4+ww)*34 + 1 + d)*44 + q4*8]) = v;
    }
    __syncthreads();

    #pragma unroll
    for(int kz=0;kz<3;kz++){
      #pragma unroll
      for(int ky=0;ky<3;ky++){
        #pragma unroll
        for(int kx=0;kx<3;kx++){
          int tap = (kz*3+ky)*3+kx;
          const bf16* wbase = wt + tap*4096 + cic + laneA;
          short8 a0 = *(const short8*)(wbase);
          short8 a1 = *(const short8*)(wbase + 1024);
          short8 a2 = *(const short8*)(wbase + 2048);
          short8 a3 = *(const short8*)(wbase + 3072);
          int rix = (kz*4 + wr + ky)*34 + dh*16 + pn + kx;
          short8 bb = *(const short8*)(&xt[rix*44 + kg8]);
          acc[0] = __builtin_amdgcn_mfma_f32_16x16x32_bf16(a0,bb,acc[0],0,0,0);
          acc[1] = __builtin_amdgcn_mfma_f32_16x16x32_bf16(a1,bb,acc[1],0,0,0);
          acc[2] = __builtin_amdgcn_mfma_f32_16x16x32_bf16(a2,bb,acc[2],0,0,0);
          acc[3] = __builtin_amdgcn_mfma_f32_16x16x32_bf16(a3,bb,acc[3],0,0,0);
        }
      }
    }
  }

  int pos = h*1024 + (w0+wr)*32 + dh*16 + pn;
  #pragma unroll
  for(int m=0;m<4;m++){
    #pragma unroll
    for(int r=0;r<4;r++){
      int oc = m*16 + quad*4 + r;
      size_t idx = ((size_t)(b*64+oc))*SP + pos;
      float v = acc[m][r] + ldin(cb, oc, f32);
      if(mode==0) out_bf[idx] = f2b(v);
      else        stout(out_any, idx, v + b2f(skip[idx]), f32);
    }
  }
}

// ---------------------------------------------------------------- instance norm + relu (in place, bf16)
__global__ void k_inorm(bf16* __restrict__ buf){
  int bc = blockIdx.x;
  bf16* p = buf + (size_t)bc*SP;
  float s=0.f, s2=0.f;
  for(int i=threadIdx.x;i<SP;i+=256){ float v=b2f(p[i]); s+=v; s2+=v*v; }
  __shared__ float sh[8];
  #pragma unroll
  for(int m=32;m>=1;m>>=1){ s += __shfl_xor(s,m); s2 += __shfl_xor(s2,m); }
  int wid = threadIdx.x>>6;
  if((threadIdx.x&63)==0){ sh[wid]=s; sh[4+wid]=s2; }
  __syncthreads();
  if(threadIdx.x==0){ float a=0,b2=0; for(int i=0;i<4;i++){a+=sh[i]; b2+=sh[4+i];} sh[0]=a; sh[4]=b2; }
  __syncthreads();
  float mean = sh[0]*(1.f/SP);
  float var  = sh[4]*(1.f/SP) - mean*mean;
  float inv = rsqrtf(fmaxf(var,0.f) + 1e-5f);
  for(int i=threadIdx.x;i<SP;i+=256){
    float v=(b2f(p[i])-mean)*inv;
    p[i] = f2b(v>0.f ? v : 0.f);
  }
}

// ---------------------------------------------------------------- per-direction prep: conv1d+silu, x_proj
__global__ void k_dirprep(const bf16* __restrict__ xz, const void* __restrict__ c1w,
                          const void* __restrict__ c1b, const void* __restrict__ xpw,
                          bf16* __restrict__ bcg, float* __restrict__ dtr,
                          const int* __restrict__ flag){
  const int f32 = *flag;
  __shared__ float xs[67][64];
  __shared__ float xcs[64][65];
  __shared__ float xws[20][65];
  int bid = blockIdx.x;
  int g = bid >> 10, b = (bid>>9)&1, tile = bid & 511;
  int l0 = tile*64;
  int gb = g*2+b;
  for(int t=threadIdx.x; t<20*64; t+=256){ int j=t>>6, d=t&63; xws[j][d]=ldin(xpw, t, f32); }
  for(int t=threadIdx.x; t<67*64; t+=256){
    int row=t>>6, d=t&63;
    int l = l0 + row - 3;
    float v = 0.f;
    if(l>=0 && l<LTOK){
      int lg = g ? (LTOK-1-l) : l;
      v = b2f(xz[((size_t)b*LTOK + lg)*128 + d]);
    }
    xs[row][d]=v;
  }
  __syncthreads();
  for(int t=threadIdx.x; t<4096; t+=256){
    int d=t&63, tl=t>>6;
    float acc = ldin(c1b, d, f32);
    #pragma unroll
    for(int k=0;k<4;k++) acc += ldin(c1w, d*4+k, f32) * xs[tl+k][d];
    xcs[tl][d] = acc / (1.f + __expf(-acc));
  }
  __syncthreads();
  for(int task=threadIdx.x; task<1280; task+=256){
    int j = task % 20, tl = task / 20;
    float acc=0.f;
    #pragma unroll
    for(int d=0; d<64; d++) acc += xcs[tl][d]*xws[j][d];
    size_t l = (size_t)gb*LTOK + l0 + tl;
    if(j<4) dtr[l*4 + j] = acc;
    else    bcg[l*16 + (j-4)] = f2b(acc);
  }
}

// ---------------------------------------------------------------- scan pass1: batched prefetch
__global__ __launch_bounds__(256, 2) void k_scan1(
                        const bf16* __restrict__ xz, const float* __restrict__ dtr,
                        const bf16* __restrict__ bcg,
                        const void* __restrict__ c1w, const void* __restrict__ c1b,
                        const void* __restrict__ dpw, const void* __restrict__ dpb,
                        const void* __restrict__ alog, const void* __restrict__ ablog,
                        float* __restrict__ psP, float* __restrict__ psS,
                        const int* __restrict__ flag){
  const int f32 = *flag;
  int wid = blockIdx.x*4 + (threadIdx.x>>6);
  int lane = threadIdx.x & 63;
  int chunk = wid & (NC-1);
  int b = (wid>>9)&1;
  int g = wid>>10;
  int gb = g*2+b;
  const void* al = g ? ablog : alog;
  float ac[8];
  #pragma unroll
  for(int n=0;n<8;n++) ac[n] = -__expf(ldin(al, lane*8+n, f32));
  float cw0=ldin(c1w,lane*4+0,f32), cw1=ldin(c1w,lane*4+1,f32), cw2=ldin(c1w,lane*4+2,f32), cw3=ldin(c1w,lane*4+3,f32);
  float cb_=ldin(c1b,lane,f32);
  float dw0=ldin(dpw,lane*4+0,f32), dw1=ldin(dpw,lane*4+1,f32), dw2=ldin(dpw,lane*4+2,f32), dw3=ldin(dpw,lane*4+3,f32);
  float db_=ldin(dpb,lane,f32);
  float S[8];
  #pragma unroll
  for(int n=0;n<8;n++) S[n]=0.f;
  float Tsum = 0.f;
  int lt0 = chunk*CLEN;
  float x0,x1,x2;
  {
    float xr[3];
    #pragma unroll
    for(int j=0;j<3;j++){
      int lt = lt0-3+j;
      float v=0.f;
      if(lt>=0){ int lg = g ? (LTOK-1-lt) : lt; v=b2f(xz[((size_t)b*LTOK+lg)*128 + lane]); }
      xr[j]=v;
    }
    x0=xr[0]; x1=xr[1]; x2=xr[2];
  }
  for(int i0=0;i0<CLEN;i0+=8){
    bf16 xv[8]; float4 dv[8]; short8 bb[8];
    #pragma unroll
    for(int k=0;k<8;k++){
      int lt = lt0+i0+k;
      int lg = g ? (LTOK-1-lt) : lt;
      xv[k] = xz[((size_t)b*LTOK+lg)*128 + lane];
      size_t l = (size_t)gb*LTOK + lt;
      dv[k] = *(const float4*)(dtr + l*4);
      bb[k] = *(const short8*)(bcg + l*16);
    }
    #pragma unroll
    for(int k=0;k<8;k++){
      float x3 = b2f(xv[k]);
      float pre = cb_ + cw0*x0 + cw1*x1 + cw2*x2 + cw3*x3;
      float xc = pre / (1.f + __expf(-pre));
      float v = db_ + dv[k].x*dw0 + dv[k].y*dw1 + dv[k].z*dw2 + dv[k].w*dw3;
      float e = __expf(-fabsf(v));
      float dt = fmaxf(v,0.f) + __logf(1.f+e);
      Tsum += dt;
      float bx = dt*xc;
      #pragma unroll
      for(int n=0;n<8;n++){
        float a = __expf(dt*ac[n]);
        S[n] = a*S[n] + bx*s2f(bb[k][n]);
      }
      x0=x1; x1=x2; x2=x3;
    }
  }
  int seq = (gb*64 + lane)*8;
  #pragma unroll
  for(int n=0;n<8;n++){
    psP[(size_t)chunk*NSEQ + seq + n] = __expf(ac[n]*Tsum);
    psS[(size_t)chunk*NSEQ + seq + n] = S[n];
  }
}

// ---------------------------------------------------------------- scan pass2: hierarchical (depth 512 -> 32/16/32)
__global__ void k_scan2a(const float* __restrict__ psP, const float* __restrict__ psS,
                         float* __restrict__ segP, float* __restrict__ segS){
  int idx = blockIdx.x*256 + threadIdx.x;       // 32768 = NSEQ*SEG
  int seq = idx & (NSEQ-1);
  int seg = idx >> 11;
  float P = 1.f, S = 0.f;
  int i0 = seg*SEGLEN;
  #pragma unroll 4
  for(int i=0;i<SEGLEN;i++){
    float p = psP[(size_t)(i0+i)*NSEQ + seq];
    float s = psS[(size_t)(i0+i)*NSEQ + seq];
    S = p*S + s;
    P *= p;
  }
  segP[seg*NSEQ + seq] = P;
  segS[seg*NSEQ + seq] = S;
}
__global__ void k_scan2b(const float* __restrict__ segP, const float* __restrict__ segS,
                         float* __restrict__ segC){
  int seq = blockIdx.x*256 + threadIdx.x;
  if(seq >= NSEQ) return;
  float h = 0.f;
  #pragma unroll
  for(int s=0;s<SEG;s++){
    segC[s*NSEQ + seq] = h;
    h = segP[s*NSEQ + seq]*h + segS[s*NSEQ + seq];
  }
}
__global__ void k_scan2c(const float* __restrict__ psP, const float* __restrict__ segC,
                         float* __restrict__ psC){
  int idx = blockIdx.x*256 + threadIdx.x;
  int seq = idx & (NSEQ-1);
  int seg = idx >> 11;
  float h = segC[seg*NSEQ + seq];
  int i0 = seg*SEGLEN;
  #pragma unroll 4
  for(int i=0;i<SEGLEN;i++){
    float p = psP[(size_t)(i0+i)*NSEQ + seq];
    float s = psC[(size_t)(i0+i)*NSEQ + seq];   // read partial BEFORE overwrite
    psC[(size_t)(i0+i)*NSEQ + seq] = h;
    h = p*h + s;
  }
}

// ---------------------------------------------------------------- scan pass3: batched prefetch, y pre-silu(z)
__global__ __launch_bounds__(256, 2) void k_scan3(
                        const bf16* __restrict__ xz, const float* __restrict__ dtr,
                        const bf16* __restrict__ bcg,
                        const void* __restrict__ c1w, const void* __restrict__ c1b,
                        const void* __restrict__ dpw, const void* __restrict__ dpb,
                        const void* __restrict__ alog, const void* __restrict__ ablog,
                        const void* __restrict__ dskip, const float* __restrict__ carry,
                        bf16* __restrict__ ybuf, const int* __restrict__ flag){
  const int f32 = *flag;
  int wid = blockIdx.x*4 + (threadIdx.x>>6);
  int lane = threadIdx.x & 63;
  int chunk = wid & (NC-1);
  int b = (wid>>9)&1;
  int g = wid>>10;
  int gb = g*2+b;
  const void* al = g ? ablog : alog;
  float ac[8];
  #pragma unroll
  for(int n=0;n<8;n++) ac[n] = -__expf(ldin(al, lane*8+n, f32));
  float cw0=ldin(c1w,lane*4+0,f32), cw1=ldin(c1w,lane*4+1,f32), cw2=ldin(c1w,lane*4+2,f32), cw3=ldin(c1w,lane*4+3,f32);
  float cb_=ldin(c1b,lane,f32);
  float dw0=ldin(dpw,lane*4+0,f32), dw1=ldin(dpw,lane*4+1,f32), dw2=ldin(dpw,lane*4+2,f32), dw3=ldin(dpw,lane*4+3,f32);
  float db_=ldin(dpb,lane,f32);
  float dsk = ldin(dskip,lane,f32);
  int seq = (gb*64 + lane)*8;
  float h[8];
  #pragma unroll
  for(int n=0;n<8;n++) h[n] = carry[(size_t)chunk*NSEQ + seq + n];
  int lt0 = chunk*CLEN;
  float x0,x1,x2;
  {
    float xr[3];
    #pragma unroll
    for(int j=0;j<3;j++){
      int lt = lt0-3+j;
      float v=0.f;
      if(lt>=0){ int lg = g ? (LTOK-1-lt) : lt; v=b2f(xz[((size_t)b*LTOK+lg)*128 + lane]); }
      xr[j]=v;
    }
    x0=xr[0]; x1=xr[1]; x2=xr[2];
  }
  for(int i0=0;i0<CLEN;i0+=8){
    bf16 xv[8]; float4 dv[8]; short8 bb[8]; short8 cc[8];
    #pragma unroll
    for(int k=0;k<8;k++){
      int lt = lt0+i0+k;
      int lg = g ? (LTOK-1-lt) : lt;
      xv[k] = xz[((size_t)b*LTOK+lg)*128 + lane];
      size_t l = (size_t)gb*LTOK + lt;
      dv[k] = *(const float4*)(dtr + l*4);
      bb[k] = *(const short8*)(bcg + l*16);
      cc[k] = *(const short8*)(bcg + l*16 + 8);
    }
    #pragma unroll
    for(int k=0;k<8;k++){
      float x3 = b2f(xv[k]);
      float pre = cb_ + cw0*x0 + cw1*x1 + cw2*x2 + cw3*x3;
      float xc = pre / (1.f + __expf(-pre));
      float v = db_ + dv[k].x*dw0 + dv[k].y*dw1 + dv[k].z*dw2 + dv[k].w*dw3;
      float e = __expf(-fabsf(v));
      float dt = fmaxf(v,0.f) + __logf(1.f+e);
      float bx = dt*xc;
      float y = xc*dsk;
      #pragma unroll
      for(int n=0;n<8;n++){
        float a = __expf(dt*ac[n]);
        h[n] = a*h[n] + bx*s2f(bb[k][n]);
        y += h[n]*s2f(cc[k][n]);
      }
      size_t l = (size_t)gb*LTOK + lt0+i0+k;
      ybuf[l*64 + lane] = f2b(y);
      x0=x1; x1=x2; x2=x3;
    }
  }
}

// ---------------------------------------------------------------- combine dirs * silu(z) + out_proj (MFMA) + LN -> vol (token-major)
__global__ __launch_bounds__(256) void k_outln(
                        const bf16* __restrict__ ybuf, const bf16* __restrict__ xz,
                        const void* __restrict__ opw,
                        const void* __restrict__ lng, const void* __restrict__ lnb,
                        bf16* __restrict__ vol_t, const int* __restrict__ flag){
  const int f32 = *flag;
  __shared__ bf16 vsm[64*72];   // [token][d] pitch 72; reused for LN output staging
  __shared__ bf16 wsm[64*72];   // [c][d]     pitch 72
  __shared__ float gsm[64], bsm[64];
  int tid = threadIdx.x;
  int b = blockIdx.x >> 9, tile = blockIdx.x & 511;
  int l0 = tile*64;

  for(int p=tid; p<512; p+=256){           // weights (c, d8)
    int c = p & 63, d8 = p >> 6;
    short8 v;
    #pragma unroll
    for(int k=0;k<8;k++){ bf16 t = f2b(ldin(opw, c*64 + d8*8 + k, f32)); v[k] = *(short*)&t; }
    *(short8*)(&wsm[c*72 + d8*8]) = v;
  }
  if(tid<64){ gsm[tid]=ldin(lng,tid,f32); bsm[tid]=ldin(lnb,tid,f32); }
  for(int p=tid; p<4096; p+=256){          // v = 0.5(yf+yb)*silu(z)
    int tl = p >> 6, d = p & 63;
    int l = l0 + tl;
    float yf = b2f(ybuf[((size_t)(0+b)*LTOK + l)*64 + d]);
    float yb = b2f(ybuf[((size_t)(2+b)*LTOK + (LTOK-1-l))*64 + d]);
    float z  = b2f(xz[((size_t)b*LTOK + l)*128 + 64 + d]);
    float sz = z / (1.f + __expf(-z));
    vsm[tl*72 + d] = f2b(0.5f*(yf+yb)*sz);
  }
  __syncthreads();

  int lane = tid & 63, wv = tid >> 6, pn = lane & 15, quad = lane >> 4, kg8 = quad*8;
  f32x4 acc[4];
  #pragma unroll
  for(int nt=0;nt<4;nt++) acc[nt]=(f32x4)(0.f);
  #pragma unroll
  for(int kq=0;kq<2;kq++){
    short8 a = *(const short8*)(&vsm[(wv*16+pn)*72 + kq*32 + kg8]);
    #pragma unroll
    for(int nt=0;nt<4;nt++){
      short8 bb = *(const short8*)(&wsm[(nt*16+pn)*72 + kq*32 + kg8]);
      acc[nt] = __builtin_amdgcn_mfma_f32_16x16x32_bf16(a,bb,acc[nt],0,0,0);
    }
  }
  __syncthreads();   // all reads of vsm done; safe to overwrite below

  float gl[4], bl[4];
  #pragma unroll
  for(int nt=0;nt<4;nt++){ gl[nt]=gsm[nt*16+pn]; bl[nt]=bsm[nt*16+pn]; }
  #pragma unroll
  for(int r=0;r<4;r++){
    float vals[4]; float s=0.f;
    #pragma unroll
    for(int nt=0;nt<4;nt++){ vals[nt]=acc[nt][r]; s+=vals[nt]; }
    #pragma unroll
    for(int m=1;m<16;m<<=1) s += __shfl_xor(s, m);
    float mu = s*(1.f/64.f);
    float s2=0.f;
    #pragma unroll
    for(int nt=0;nt<4;nt++){ float dv=vals[nt]-mu; s2+=dv*dv; }
    #pragma unroll
    for(int m=1;m<16;m<<=1) s2 += __shfl_xor(s2, m);
    float inv = rsqrtf(s2*(1.f/64.f) + 1e-5f);
    int token = wv*16 + quad*4 + r;
    #pragma unroll
    for(int nt=0;nt<4;nt++){
      vsm[token*72 + nt*16 + pn] = f2b((vals[nt]-mu)*inv*gl[nt] + bl[nt]);
    }
  }
  __syncthreads();
  for(int p=tid; p<512; p+=256){           // coalesced token-major short8 stores
    int tl = p >> 3, d8 = p & 7;
    *(short8*)(&vol_t[((size_t)b*SP + l0 + tl)*64 + d8*8]) = *(const short8*)(&vsm[tl*72 + d8*8]);
  }
}

// ---------------------------------------------------------------- launch
extern "C" void kernel_launch(void* const* d_in, const int* in_sizes, int n_in,
                              void* d_out, int out_size, void* d_ws, size_t ws_size,
                              hipStream_t stream){
  const void* input  = d_in[0];
  const void* conv_w = d_in[1];
  const void* conv_b = d_in[2];
  const void* inpw   = d_in[3];
  const void* c1w    = d_in[4];
  const void* c1b    = d_in[5];
  const void* xpw    = d_in[6];
  const void* dpw    = d_in[7];
  const void* dpb    = d_in[8];
  const void* alog   = d_in[9];
  const void* ablog  = d_in[10];
  const void* dskip  = d_in[11];
  const void* opw    = d_in[12];
  const void* lng    = d_in[13];
  const void* lnb    = d_in[14];

  char* base = (char*)d_ws;
  bf16*  skipb = (bf16*) (base + 0);            //  8,388,608 B
  bf16*  xz    = (bf16*) (base + 8388608);      // 16,777,216 B
  bf16*  bcg   = (bf16*) (base + 25165824);     //  4,194,304 B
  float* dtr   = (float*)(base + 29360128);     //  2,097,152 B
  float* psP   = (float*)(base + 31457280);     //  4,194,304 B
  float* psS   = (float*)(base + 35651584);     //  4,194,304 B (reused in-place as carry)
  bf16*  ybuf  = (bf16*) (base + 39845888);     // 16,777,216 B
  bf16*  wt    = (bf16*) (base + 56623104);     //    221,184 B (ends 56,844,288)
  float* segP  = (float*)(base + 56844288);     //    131,072 B
  float* segS  = (float*)(base + 56975360);     //    131,072 B
  float* segC  = (float*)(base + 57106432);     //    131,072 B (ends 57,237,504)
  bf16*  xin_t = (bf16*) (base + 31457280);     //  8,388,608 B alias psP+psS (dead until scan1)
  bf16*  vol_t = (bf16*) (base + 25165824);     //  8,388,608 B alias bcg+dtr+psP[0:2.1M] (dead after scan2/scan3)
  int*   flagp = (int*)  (base + 60817408);     //  16 B
  const size_t NEED = 60817424;

  k_detect<<<dim3(1), dim3(64), 0, stream>>>(conv_w, flagp);

  if(ws_size < NEED){
    k_fill<<<dim3((out_size+255)/256), dim3(256), 0, stream>>>(d_out, out_size, flagp);
    return;
  }

  k_wprep  <<<dim3(432),   dim3(256), 0, stream>>>(conv_w, wt, flagp);
  k_inprojm<<<dim3(512),   dim3(256), 0, stream>>>(input, inpw, xz, xin_t, flagp);
  // conv #1: xin_t -> skipb (bf16, channel-major out)
  k_convm  <<<dim3(1024),  dim3(256), 0, stream>>>(xin_t, wt, conv_b, nullptr, skipb, nullptr, 0, flagp);
  k_inorm  <<<dim3(128),   dim3(256), 0, stream>>>(skipb);
  k_dirprep<<<dim3(2048),  dim3(256), 0, stream>>>(xz, c1w, c1b, xpw, bcg, dtr, flagp);
  k_scan1  <<<dim3(512),   dim3(256), 0, stream>>>(xz, dtr, bcg, c1w, c1b, dpw, dpb, alog, ablog, psP, psS, flagp);
  k_scan2a <<<dim3(128),   dim3(256), 0, stream>>>(psP, psS, segP, segS);
  k_scan2b <<<dim3(8),     dim3(256), 0, stream>>>(segP, segS, segC);
  k_scan2c <<<dim3(128),   dim3(256), 0, stream>>>(psP, segC, psS);
  k_scan3  <<<dim3(512),   dim3(256), 0, stream>>>(xz, dtr, bcg, c1w, c1b, dpw, dpb, alog, ablog, dskip, psS, ybuf, flagp);
  k_outln  <<<dim3(1024),  dim3(256), 0, stream>>>(ybuf, xz, opw, lng, lnb, vol_t, flagp);
  // conv #2: vol_t (+skipb) -> d_out, dual-dtype out
  k_convm  <<<dim3(1024),  dim3(256), 0, stream>>>(vol_t, wt, conv_b, skipb, nullptr, d_out, 1, flagp);
}

// Round 11
// 464.253 us; speedup vs baseline: 1.1847x; 1.1847x over previous
//
#include <hip/hip_runtime.h>
#include <hip/hip_bf16.h>

typedef __hip_bfloat16 bf16;
typedef __attribute__((ext_vector_type(8))) short short8;   // 8 bf16 = 4 VGPRs
typedef __attribute__((ext_vector_type(4))) float f32x4;    // MFMA acc

__device__ __forceinline__ float b2f(bf16 x){ return __bfloat162float(x); }
__device__ __forceinline__ bf16  f2b(float x){ return __float2bfloat16(x); }
__device__ __forceinline__ float s2f(short s){ bf16 t = *(bf16*)&s; return b2f(t); }

// dual-dtype input load / output store (flag: 1 = fp32 storage, 0 = bf16)
__device__ __forceinline__ float ldin(const void* p, size_t i, int f32){
  return f32 ? ((const float*)p)[i] : b2f(((const bf16*)p)[i]);
}
__device__ __forceinline__ void stout(void* p, size_t i, float v, int f32){
  if(f32) ((float*)p)[i] = v; else ((bf16*)p)[i] = f2b(v);
}

constexpr int SP   = 32*32*32;   // 32768 spatial per (b,c)
constexpr int LTOK = SP;         // tokens per batch
constexpr int NC   = 512;        // scan chunks
constexpr int CLEN = LTOK / NC;  // 64
constexpr int NSEQ = 2*2*64*8;   // 2048 scan sequences (dir,b,d,n)
constexpr int SEG  = 16;         // scan2 hierarchy: 16 segments x 32 chunks
constexpr int SEGLEN = NC/SEG;   // 32

// ---------------------------------------------------------------- dtype detector
__global__ void k_detect(const void* conv_w, int* flag){
  if(threadIdx.x==0 && blockIdx.x==0){
    const bf16* p = (const bf16*)conv_w;
    int f = 0;
    for(int i=0;i<128;i++){
      float v = b2f(p[i]);
      if(!(v==v) || fabsf(v) > 1.0f) f = 1;   // bf16 weights are 0.05-scale
    }
    *flag = f;
  }
}

// ---------------------------------------------------------------- diagnostic fill
__global__ void k_fill(void* out, int n, const int* flag){
  const int f32 = *flag;
  int i = blockIdx.x*256 + threadIdx.x;
  if(i<n) stout(out, i, 12345.0f, f32);
}

// ---------------------------------------------------------------- weight re-layout: wt[tap][oc][ci]
__global__ void k_wprep(const void* __restrict__ cw, bf16* __restrict__ wt,
                        const int* __restrict__ flag){
  const int f32 = *flag;
  int t = blockIdx.x*256 + threadIdx.x;   // 110592 = 27*64*64
  if(t >= 27*64*64) return;
  int tap = t >> 12;          // /4096
  int oc  = (t >> 6) & 63;
  int ci  = t & 63;
  wt[t] = f2b(ldin(cw, ((size_t)(oc*64+ci))*27 + tap, f32));
}

// ---------------------------------------------------------------- in_proj as MFMA GEMM
__global__ __launch_bounds__(256) void k_inprojm(
    const void* __restrict__ in, const void* __restrict__ pw,
    bf16* __restrict__ xz, bf16* __restrict__ xin_t,
    const int* __restrict__ flag){
  const int f32 = *flag;
  __shared__ bf16 tok[128*72];   // [token][c], pitch 72
  __shared__ bf16 wl [128*72];   // [j][c],     pitch 72
  int tid = threadIdx.x;
  int b = blockIdx.x >> 8, tile = blockIdx.x & 255;
  int l0 = tile*128;

  for(int p=tid; p<1024; p+=256){          // weights: (j, c8)
    int j = p & 127, c8 = p >> 7;
    short8 v;
    #pragma unroll
    for(int k=0;k<8;k++){
      bf16 t = f2b(ldin(pw, j*64 + c8*8 + k, f32));
      v[k] = *(short*)&t;
    }
    *(short8*)(&wl[j*72 + c8*8]) = v;
  }
  for(int p=tid; p<1024; p+=256){          // tokens: (i, c8), coalesced over i
    int i = p & 127, c8 = p >> 7;
    short8 v;
    #pragma unroll
    for(int k=0;k<8;k++){
      bf16 t = f2b(ldin(in, ((size_t)(b*64 + c8*8 + k))*SP + l0 + i, f32));
      v[k] = *(short*)&t;
    }
    *(short8*)(&tok[i*72 + c8*8]) = v;
  }
  __syncthreads();

  int lane = tid & 63, wv = tid >> 6;
  int pn = lane & 15, quad = lane >> 4, kg8 = quad*8;
  f32x4 acc[2][8];
  #pragma unroll
  for(int mt=0;mt<2;mt++)
    #pragma unroll
    for(int nt=0;nt<8;nt++) acc[mt][nt]=(f32x4)(0.f);

  #pragma unroll
  for(int kq=0;kq<2;kq++){
    short8 a0 = *(const short8*)(&tok[(wv*32      + pn)*72 + kq*32 + kg8]);
    short8 a1 = *(const short8*)(&tok[(wv*32 + 16 + pn)*72 + kq*32 + kg8]);
    #pragma unroll
    for(int nt=0;nt<8;nt++){
      short8 bb = *(const short8*)(&wl[(nt*16+pn)*72 + kq*32 + kg8]);
      acc[0][nt] = __builtin_amdgcn_mfma_f32_16x16x32_bf16(a0,bb,acc[0][nt],0,0,0);
      acc[1][nt] = __builtin_amdgcn_mfma_f32_16x16x32_bf16(a1,bb,acc[1][nt],0,0,0);
    }
  }

  #pragma unroll
  for(int mt=0;mt<2;mt++){
    #pragma unroll
    for(int nt=0;nt<8;nt++){
      #pragma unroll
      for(int r=0;r<4;r++){
        int token = wv*32 + mt*16 + quad*4 + r;
        xz[((size_t)b*LTOK + l0 + token)*128 + nt*16 + pn] = f2b(acc[mt][nt][r]);
      }
    }
  }
  for(int p=tid; p<8192; p+=256){
    int i = p >> 6, c = p & 63;
    xin_t[((size_t)b*SP + l0 + i)*64 + c] = tok[i*72 + c];
  }
}

// ---------------------------------------------------------------- MFMA conv3d (both convs)
// R11: exact R8 structure (best measured: 71 us) with ONE delta — LDS pitch
// 40 -> 44 elements. Pitch-40 gives B-frag word-stride 20 (8-way bank alias,
// 1.18M conflicts); pitch-44 gives stride 22 -> 16 distinct banks (405K).
__global__ __launch_bounds__(256, 2) void k_convm(
    const bf16* __restrict__ xin_t, const bf16* __restrict__ wt,
    const void* __restrict__ cb, const bf16* __restrict__ skip,
    bf16* __restrict__ out_bf, void* __restrict__ out_any,
    int mode, const int* __restrict__ flag){
  const int f32 = *flag;
  __shared__ bf16 xt[612*44];   // [ (hh*6+ww)*34 + dd ][ 44 ] = 53,856 B

  int tid  = threadIdx.x;
  int lane = tid & 63;
  int wv   = tid >> 6;
  int pn   = lane & 15;
  int quad = lane >> 4;
  int kg8  = quad * 8;
  int laneA = pn*64 + kg8;

  int blk = blockIdx.x;         // 512 = 2b * 32h * 8wgrp
  int b  = blk >> 8;
  int h  = (blk >> 3) & 31;
  int w0 = (blk & 7) * 4;

  f32x4 acc[4][2];
  #pragma unroll
  for(int m=0;m<4;m++){ acc[m][0]=(f32x4)(0.f); acc[m][1]=(f32x4)(0.f); }

  for(int cic=0; cic<64; cic+=32){
    if(cic) __syncthreads();
    if(cic==0){
      for(int i=tid; i<36*2*32; i+=256){   // zero d-halo rows (dd=0,33)
        int cil = i & 31; int q = i >> 5;
        int hw = q >> 1;  int dd = (q & 1) ? 33 : 0;
        xt[(hw*34 + dd)*44 + cil] = f2b(0.f);
      }
    }
    #pragma unroll
    for(int it=0; it<9; it++){
      int row = it*64 + (tid>>2);
      int q4  = tid & 3;
      int d   = row & 31;
      int hw  = row >> 5;
      int ww  = hw % 6, hh = hw / 6;
      int hg = h + hh - 1, wg = w0 + ww - 1;
      short8 v = (short8)(0);
      if((unsigned)hg < 32u && (unsigned)wg < 32u)
        v = *(const short8*)(&xin_t[(((size_t)b*SP) + hg*1024 + wg*32 + d)*64 + cic + q4*8]);
      *(short8*)(&xt[(hw*34 + 1 + d)*44 + q4*8]) = v;
    }
    __syncthreads();

    #pragma unroll
    for(int kz=0;kz<3;kz++){
      #pragma unroll
      for(int ky=0;ky<3;ky++){
        #pragma unroll
        for(int kx=0;kx<3;kx++){
          int tap = (kz*3+ky)*3+kx;
          const bf16* wbase = wt + tap*4096 + cic + laneA;
          short8 a0 = *(const short8*)(wbase);
          short8 a1 = *(const short8*)(wbase + 1024);
          short8 a2 = *(const short8*)(wbase + 2048);
          short8 a3 = *(const short8*)(wbase + 3072);
          int rix = (kz*6 + wv + ky)*34 + pn + kx;
          short8 b0 = *(const short8*)(&xt[ rix     *44 + kg8]);
          short8 b1 = *(const short8*)(&xt[(rix+16) *44 + kg8]);
          acc[0][0] = __builtin_amdgcn_mfma_f32_16x16x32_bf16(a0,b0,acc[0][0],0,0,0);
          acc[0][1] = __builtin_amdgcn_mfma_f32_16x16x32_bf16(a0,b1,acc[0][1],0,0,0);
          acc[1][0] = __builtin_amdgcn_mfma_f32_16x16x32_bf16(a1,b0,acc[1][0],0,0,0);
          acc[1][1] = __builtin_amdgcn_mfma_f32_16x16x32_bf16(a1,b1,acc[1][1],0,0,0);
          acc[2][0] = __builtin_amdgcn_mfma_f32_16x16x32_bf16(a2,b0,acc[2][0],0,0,0);
          acc[2][1] = __builtin_amdgcn_mfma_f32_16x16x32_bf16(a2,b1,acc[2][1],0,0,0);
          acc[3][0] = __builtin_amdgcn_mfma_f32_16x16x32_bf16(a3,b0,acc[3][0],0,0,0);
          acc[3][1] = __builtin_amdgcn_mfma_f32_16x16x32_bf16(a3,b1,acc[3][1],0,0,0);
        }
      }
    }
  }

  int posbase = h*1024 + (w0+wv)*32;
  #pragma unroll
  for(int m=0;m<4;m++){
    #pragma unroll
    for(int t=0;t<2;t++){
      #pragma unroll
      for(int r=0;r<4;r++){
        int oc = m*16 + quad*4 + r;
        size_t idx = ((size_t)(b*64+oc))*SP + posbase + t*16 + pn;
        float v = acc[m][t][r] + ldin(cb, oc, f32);
        if(mode==0) out_bf[idx] = f2b(v);
        else        stout(out_any, idx, v + b2f(skip[idx]), f32);
      }
    }
  }
}

// ---------------------------------------------------------------- instance norm + relu (in place, bf16)
__global__ void k_inorm(bf16* __restrict__ buf){
  int bc = blockIdx.x;
  bf16* p = buf + (size_t)bc*SP;
  float s=0.f, s2=0.f;
  for(int i=threadIdx.x;i<SP;i+=256){ float v=b2f(p[i]); s+=v; s2+=v*v; }
  __shared__ float sh[8];
  #pragma unroll
  for(int m=32;m>=1;m>>=1){ s += __shfl_xor(s,m); s2 += __shfl_xor(s2,m); }
  int wid = threadIdx.x>>6;
  if((threadIdx.x&63)==0){ sh[wid]=s; sh[4+wid]=s2; }
  __syncthreads();
  if(threadIdx.x==0){ float a=0,b2=0; for(int i=0;i<4;i++){a+=sh[i]; b2+=sh[4+i];} sh[0]=a; sh[4]=b2; }
  __syncthreads();
  float mean = sh[0]*(1.f/SP);
  float var  = sh[4]*(1.f/SP) - mean*mean;
  float inv = rsqrtf(fmaxf(var,0.f) + 1e-5f);
  for(int i=threadIdx.x;i<SP;i+=256){
    float v=(b2f(p[i])-mean)*inv;
    p[i] = f2b(v>0.f ? v : 0.f);
  }
}

// ---------------------------------------------------------------- per-direction prep: conv1d+silu, x_proj
__global__ void k_dirprep(const bf16* __restrict__ xz, const void* __restrict__ c1w,
                          const void* __restrict__ c1b, const void* __restrict__ xpw,
                          bf16* __restrict__ bcg, float* __restrict__ dtr,
                          const int* __restrict__ flag){
  const int f32 = *flag;
  __shared__ float xs[67][64];
  __shared__ float xcs[64][65];
  __shared__ float xws[20][65];
  int bid = blockIdx.x;
  int g = bid >> 10, b = (bid>>9)&1, tile = bid & 511;
  int l0 = tile*64;
  int gb = g*2+b;
  for(int t=threadIdx.x; t<20*64; t+=256){ int j=t>>6, d=t&63; xws[j][d]=ldin(xpw, t, f32); }
  for(int t=threadIdx.x; t<67*64; t+=256){
    int row=t>>6, d=t&63;
    int l = l0 + row - 3;
    float v = 0.f;
    if(l>=0 && l<LTOK){
      int lg = g ? (LTOK-1-l) : l;
      v = b2f(xz[((size_t)b*LTOK + lg)*128 + d]);
    }
    xs[row][d]=v;
  }
  __syncthreads();
  for(int t=threadIdx.x; t<4096; t+=256){
    int d=t&63, tl=t>>6;
    float acc = ldin(c1b, d, f32);
    #pragma unroll
    for(int k=0;k<4;k++) acc += ldin(c1w, d*4+k, f32) * xs[tl+k][d];
    xcs[tl][d] = acc / (1.f + __expf(-acc));
  }
  __syncthreads();
  for(int task=threadIdx.x; task<1280; task+=256){
    int j = task % 20, tl = task / 20;
    float acc=0.f;
    #pragma unroll
    for(int d=0; d<64; d++) acc += xcs[tl][d]*xws[j][d];
    size_t l = (size_t)gb*LTOK + l0 + tl;
    if(j<4) dtr[l*4 + j] = acc;
    else    bcg[l*16 + (j-4)] = f2b(acc);
  }
}

// ---------------------------------------------------------------- scan pass1: batched prefetch
__global__ __launch_bounds__(256, 2) void k_scan1(
                        const bf16* __restrict__ xz, const float* __restrict__ dtr,
                        const bf16* __restrict__ bcg,
                        const void* __restrict__ c1w, const void* __restrict__ c1b,
                        const void* __restrict__ dpw, const void* __restrict__ dpb,
                        const void* __restrict__ alog, const void* __restrict__ ablog,
                        float* __restrict__ psP, float* __restrict__ psS,
                        const int* __restrict__ flag){
  const int f32 = *flag;
  int wid = blockIdx.x*4 + (threadIdx.x>>6);
  int lane = threadIdx.x & 63;
  int chunk = wid & (NC-1);
  int b = (wid>>9)&1;
  int g = wid>>10;
  int gb = g*2+b;
  const void* al = g ? ablog : alog;
  float ac[8];
  #pragma unroll
  for(int n=0;n<8;n++) ac[n] = -__expf(ldin(al, lane*8+n, f32));
  float cw0=ldin(c1w,lane*4+0,f32), cw1=ldin(c1w,lane*4+1,f32), cw2=ldin(c1w,lane*4+2,f32), cw3=ldin(c1w,lane*4+3,f32);
  float cb_=ldin(c1b,lane,f32);
  float dw0=ldin(dpw,lane*4+0,f32), dw1=ldin(dpw,lane*4+1,f32), dw2=ldin(dpw,lane*4+2,f32), dw3=ldin(dpw,lane*4+3,f32);
  float db_=ldin(dpb,lane,f32);
  float S[8];
  #pragma unroll
  for(int n=0;n<8;n++) S[n]=0.f;
  float Tsum = 0.f;
  int lt0 = chunk*CLEN;
  float x0,x1,x2;
  {
    float xr[3];
    #pragma unroll
    for(int j=0;j<3;j++){
      int lt = lt0-3+j;
      float v=0.f;
      if(lt>=0){ int lg = g ? (LTOK-1-lt) : lt; v=b2f(xz[((size_t)b*LTOK+lg)*128 + lane]); }
      xr[j]=v;
    }
    x0=xr[0]; x1=xr[1]; x2=xr[2];
  }
  for(int i0=0;i0<CLEN;i0+=8){
    bf16 xv[8]; float4 dv[8]; short8 bb[8];
    #pragma unroll
    for(int k=0;k<8;k++){
      int lt = lt0+i0+k;
      int lg = g ? (LTOK-1-lt) : lt;
      xv[k] = xz[((size_t)b*LTOK+lg)*128 + lane];
      size_t l = (size_t)gb*LTOK + lt;
      dv[k] = *(const float4*)(dtr + l*4);
      bb[k] = *(const short8*)(bcg + l*16);
    }
    #pragma unroll
    for(int k=0;k<8;k++){
      float x3 = b2f(xv[k]);
      float pre = cb_ + cw0*x0 + cw1*x1 + cw2*x2 + cw3*x3;
      float xc = pre / (1.f + __expf(-pre));
      float v = db_ + dv[k].x*dw0 + dv[k].y*dw1 + dv[k].z*dw2 + dv[k].w*dw3;
      float e = __expf(-fabsf(v));
      float dt = fmaxf(v,0.f) + __logf(1.f+e);
      Tsum += dt;
      float bx = dt*xc;
      #pragma unroll
      for(int n=0;n<8;n++){
        float a = __expf(dt*ac[n]);
        S[n] = a*S[n] + bx*s2f(bb[k][n]);
      }
      x0=x1; x1=x2; x2=x3;
    }
  }
  int seq = (gb*64 + lane)*8;
  #pragma unroll
  for(int n=0;n<8;n++){
    psP[(size_t)chunk*NSEQ + seq + n] = __expf(ac[n]*Tsum);
    psS[(size_t)chunk*NSEQ + seq + n] = S[n];
  }
}

// ---------------------------------------------------------------- scan pass2: hierarchical (depth 512 -> 32/16/32)
__global__ void k_scan2a(const float* __restrict__ psP, const float* __restrict__ psS,
                         float* __restrict__ segP, float* __restrict__ segS){
  int idx = blockIdx.x*256 + threadIdx.x;       // 32768 = NSEQ*SEG
  int seq = idx & (NSEQ-1);
  int seg = idx >> 11;
  float P = 1.f, S = 0.f;
  int i0 = seg*SEGLEN;
  #pragma unroll 4
  for(int i=0;i<SEGLEN;i++){
    float p = psP[(size_t)(i0+i)*NSEQ + seq];
    float s = psS[(size_t)(i0+i)*NSEQ + seq];
    S = p*S + s;
    P *= p;
  }
  segP[seg*NSEQ + seq] = P;
  segS[seg*NSEQ + seq] = S;
}
__global__ void k_scan2b(const float* __restrict__ segP, const float* __restrict__ segS,
                         float* __restrict__ segC){
  int seq = blockIdx.x*256 + threadIdx.x;
  if(seq >= NSEQ) return;
  float h = 0.f;
  #pragma unroll
  for(int s=0;s<SEG;s++){
    segC[s*NSEQ + seq] = h;
    h = segP[s*NSEQ + seq]*h + segS[s*NSEQ + seq];
  }
}
__global__ void k_scan2c(const float* __restrict__ psP, const float* __restrict__ segC,
                         float* __restrict__ psC){
  int idx = blockIdx.x*256 + threadIdx.x;
  int seq = idx & (NSEQ-1);
  int seg = idx >> 11;
  float h = segC[seg*NSEQ + seq];
  int i0 = seg*SEGLEN;
  #pragma unroll 4
  for(int i=0;i<SEGLEN;i++){
    float p = psP[(size_t)(i0+i)*NSEQ + seq];
    float s = psC[(size_t)(i0+i)*NSEQ + seq];   // read partial BEFORE overwrite
    psC[(size_t)(i0+i)*NSEQ + seq] = h;
    h = p*h + s;
  }
}

// ---------------------------------------------------------------- scan pass3: batched prefetch, y pre-silu(z)
__global__ __launch_bounds__(256, 2) void k_scan3(
                        const bf16* __restrict__ xz, const float* __restrict__ dtr,
                        const bf16* __restrict__ bcg,
                        const void* __restrict__ c1w, const void* __restrict__ c1b,
                        const void* __restrict__ dpw, const void* __restrict__ dpb,
                        const void* __restrict__ alog, const void* __restrict__ ablog,
                        const void* __restrict__ dskip, const float* __restrict__ carry,
                        bf16* __restrict__ ybuf, const int* __restrict__ flag){
  const int f32 = *flag;
  int wid = blockIdx.x*4 + (threadIdx.x>>6);
  int lane = threadIdx.x & 63;
  int chunk = wid & (NC-1);
  int b = (wid>>9)&1;
  int g = wid>>10;
  int gb = g*2+b;
  const void* al = g ? ablog : alog;
  float ac[8];
  #pragma unroll
  for(int n=0;n<8;n++) ac[n] = -__expf(ldin(al, lane*8+n, f32));
  float cw0=ldin(c1w,lane*4+0,f32), cw1=ldin(c1w,lane*4+1,f32), cw2=ldin(c1w,lane*4+2,f32), cw3=ldin(c1w,lane*4+3,f32);
  float cb_=ldin(c1b,lane,f32);
  float dw0=ldin(dpw,lane*4+0,f32), dw1=ldin(dpw,lane*4+1,f32), dw2=ldin(dpw,lane*4+2,f32), dw3=ldin(dpw,lane*4+3,f32);
  float db_=ldin(dpb,lane,f32);
  float dsk = ldin(dskip,lane,f32);
  int seq = (gb*64 + lane)*8;
  float h[8];
  #pragma unroll
  for(int n=0;n<8;n++) h[n] = carry[(size_t)chunk*NSEQ + seq + n];
  int lt0 = chunk*CLEN;
  float x0,x1,x2;
  {
    float xr[3];
    #pragma unroll
    for(int j=0;j<3;j++){
      int lt = lt0-3+j;
      float v=0.f;
      if(lt>=0){ int lg = g ? (LTOK-1-lt) : lt; v=b2f(xz[((size_t)b*LTOK+lg)*128 + lane]); }
      xr[j]=v;
    }
    x0=xr[0]; x1=xr[1]; x2=xr[2];
  }
  for(int i0=0;i0<CLEN;i0+=8){
    bf16 xv[8]; float4 dv[8]; short8 bb[8]; short8 cc[8];
    #pragma unroll
    for(int k=0;k<8;k++){
      int lt = lt0+i0+k;
      int lg = g ? (LTOK-1-lt) : lt;
      xv[k] = xz[((size_t)b*LTOK+lg)*128 + lane];
      size_t l = (size_t)gb*LTOK + lt;
      dv[k] = *(const float4*)(dtr + l*4);
      bb[k] = *(const short8*)(bcg + l*16);
      cc[k] = *(const short8*)(bcg + l*16 + 8);
    }
    #pragma unroll
    for(int k=0;k<8;k++){
      float x3 = b2f(xv[k]);
      float pre = cb_ + cw0*x0 + cw1*x1 + cw2*x2 + cw3*x3;
      float xc = pre / (1.f + __expf(-pre));
      float v = db_ + dv[k].x*dw0 + dv[k].y*dw1 + dv[k].z*dw2 + dv[k].w*dw3;
      float e = __expf(-fabsf(v));
      float dt = fmaxf(v,0.f) + __logf(1.f+e);
      float bx = dt*xc;
      float y = xc*dsk;
      #pragma unroll
      for(int n=0;n<8;n++){
        float a = __expf(dt*ac[n]);
        h[n] = a*h[n] + bx*s2f(bb[k][n]);
        y += h[n]*s2f(cc[k][n]);
      }
      size_t l = (size_t)gb*LTOK + lt0+i0+k;
      ybuf[l*64 + lane] = f2b(y);
      x0=x1; x1=x2; x2=x3;
    }
  }
}

// ---------------------------------------------------------------- combine dirs * silu(z) + out_proj (MFMA) + LN -> vol (token-major)
__global__ __launch_bounds__(256) void k_outln(
                        const bf16* __restrict__ ybuf, const bf16* __restrict__ xz,
                        const void* __restrict__ opw,
                        const void* __restrict__ lng, const void* __restrict__ lnb,
                        bf16* __restrict__ vol_t, const int* __restrict__ flag){
  const int f32 = *flag;
  __shared__ bf16 vsm[64*72];   // [token][d] pitch 72; reused for LN output staging
  __shared__ bf16 wsm[64*72];   // [c][d]     pitch 72
  __shared__ float gsm[64], bsm[64];
  int tid = threadIdx.x;
  int b = blockIdx.x >> 9, tile = blockIdx.x & 511;
  int l0 = tile*64;

  for(int p=tid; p<512; p+=256){           // weights (c, d8)
    int c = p & 63, d8 = p >> 6;
    short8 v;
    #pragma unroll
    for(int k=0;k<8;k++){ bf16 t = f2b(ldin(opw, c*64 + d8*8 + k, f32)); v[k] = *(short*)&t; }
    *(short8*)(&wsm[c*72 + d8*8]) = v;
  }
  if(tid<64){ gsm[tid]=ldin(lng,tid,f32); bsm[tid]=ldin(lnb,tid,f32); }
  for(int p=tid; p<4096; p+=256){          // v = 0.5(yf+yb)*silu(z)
    int tl = p >> 6, d = p & 63;
    int l = l0 + tl;
    float yf = b2f(ybuf[((size_t)(0+b)*LTOK + l)*64 + d]);
    float yb = b2f(ybuf[((size_t)(2+b)*LTOK + (LTOK-1-l))*64 + d]);
    float z  = b2f(xz[((size_t)b*LTOK + l)*128 + 64 + d]);
    float sz = z / (1.f + __expf(-z));
    vsm[tl*72 + d] = f2b(0.5f*(yf+yb)*sz);
  }
  __syncthreads();

  int lane = tid & 63, wv = tid >> 6, pn = lane & 15, quad = lane >> 4, kg8 = quad*8;
  f32x4 acc[4];
  #pragma unroll
  for(int nt=0;nt<4;nt++) acc[nt]=(f32x4)(0.f);
  #pragma unroll
  for(int kq=0;kq<2;kq++){
    short8 a = *(const short8*)(&vsm[(wv*16+pn)*72 + kq*32 + kg8]);
    #pragma unroll
    for(int nt=0;nt<4;nt++){
      short8 bb = *(const short8*)(&wsm[(nt*16+pn)*72 + kq*32 + kg8]);
      acc[nt] = __builtin_amdgcn_mfma_f32_16x16x32_bf16(a,bb,acc[nt],0,0,0);
    }
  }
  __syncthreads();   // all reads of vsm done; safe to overwrite below

  float gl[4], bl[4];
  #pragma unroll
  for(int nt=0;nt<4;nt++){ gl[nt]=gsm[nt*16+pn]; bl[nt]=bsm[nt*16+pn]; }
  #pragma unroll
  for(int r=0;r<4;r++){
    float vals[4]; float s=0.f;
    #pragma unroll
    for(int nt=0;nt<4;nt++){ vals[nt]=acc[nt][r]; s+=vals[nt]; }
    #pragma unroll
    for(int m=1;m<16;m<<=1) s += __shfl_xor(s, m);
    float mu = s*(1.f/64.f);
    float s2=0.f;
    #pragma unroll
    for(int nt=0;nt<4;nt++){ float dv=vals[nt]-mu; s2+=dv*dv; }
    #pragma unroll
    for(int m=1;m<16;m<<=1) s2 += __shfl_xor(s2, m);
    float inv = rsqrtf(s2*(1.f/64.f) + 1e-5f);
    int token = wv*16 + quad*4 + r;
    #pragma unroll
    for(int nt=0;nt<4;nt++){
      vsm[token*72 + nt*16 + pn] = f2b((vals[nt]-mu)*inv*gl[nt] + bl[nt]);
    }
  }
  __syncthreads();
  for(int p=tid; p<512; p+=256){           // coalesced token-major short8 stores
    int tl = p >> 3, d8 = p & 7;
    *(short8*)(&vol_t[((size_t)b*SP + l0 + tl)*64 + d8*8]) = *(const short8*)(&vsm[tl*72 + d8*8]);
  }
}

// ---------------------------------------------------------------- launch
extern "C" void kernel_launch(void* const* d_in, const int* in_sizes, int n_in,
                              void* d_out, int out_size, void* d_ws, size_t ws_size,
                              hipStream_t stream){
  const void* input  = d_in[0];
  const void* conv_w = d_in[1];
  const void* conv_b = d_in[2];
  const void* inpw   = d_in[3];
  const void* c1w    = d_in[4];
  const void* c1b    = d_in[5];
  const void* xpw    = d_in[6];
  const void* dpw    = d_in[7];
  const void* dpb    = d_in[8];
  const void* alog   = d_in[9];
  const void* ablog  = d_in[10];
  const void* dskip  = d_in[11];
  const void* opw    = d_in[12];
  const void* lng    = d_in[13];
  const void* lnb    = d_in[14];

  char* base = (char*)d_ws;
  bf16*  skipb = (bf16*) (base + 0);            //  8,388,608 B
  bf16*  xz    = (bf16*) (base + 8388608);      // 16,777,216 B
  bf16*  bcg   = (bf16*) (base + 25165824);     //  4,194,304 B
  float* dtr   = (float*)(base + 29360128);     //  2,097,152 B
  float* psP   = (float*)(base + 31457280);     //  4,194,304 B
  float* psS   = (float*)(base + 35651584);     //  4,194,304 B (reused in-place as carry)
  bf16*  ybuf  = (bf16*) (base + 39845888);     // 16,777,216 B
  bf16*  wt    = (bf16*) (base + 56623104);     //    221,184 B (ends 56,844,288)
  float* segP  = (float*)(base + 56844288);     //    131,072 B
  float* segS  = (float*)(base + 56975360);     //    131,072 B
  float* segC  = (float*)(base + 57106432);     //    131,072 B (ends 57,237,504)
  bf16*  xin_t = (bf16*) (base + 31457280);     //  8,388,608 B alias psP+psS (dead until scan1)
  bf16*  vol_t = (bf16*) (base + 25165824);     //  8,388,608 B alias bcg+dtr+psP[0:2.1M] (dead after scan2/scan3)
  int*   flagp = (int*)  (base + 60817408);     //  16 B
  const size_t NEED = 60817424;

  k_detect<<<dim3(1), dim3(64), 0, stream>>>(conv_w, flagp);

  if(ws_size < NEED){
    k_fill<<<dim3((out_size+255)/256), dim3(256), 0, stream>>>(d_out, out_size, flagp);
    return;
  }

  k_wprep  <<<dim3(432),   dim3(256), 0, stream>>>(conv_w, wt, flagp);
  k_inprojm<<<dim3(512),   dim3(256), 0, stream>>>(input, inpw, xz, xin_t, flagp);
  // conv #1: xin_t -> skipb (bf16, channel-major out)
  k_convm  <<<dim3(512),   dim3(256), 0, stream>>>(xin_t, wt, conv_b, nullptr, skipb, nullptr, 0, flagp);
  k_inorm  <<<dim3(128),   dim3(256), 0, stream>>>(skipb);
  k_dirprep<<<dim3(2048),  dim3(256), 0, stream>>>(xz, c1w, c1b, xpw, bcg, dtr, flagp);
  k_scan1  <<<dim3(512),   dim3(256), 0, stream>>>(xz, dtr, bcg, c1w, c1b, dpw, dpb, alog, ablog, psP, psS, flagp);
  k_scan2a <<<dim3(128),   dim3(256), 0, stream>>>(psP, psS, segP, segS);
  k_scan2b <<<dim3(8),     dim3(256), 0, stream>>>(segP, segS, segC);
  k_scan2c <<<dim3(128),   dim3(256), 0, stream>>>(psP, segC, psS);
  k_scan3  <<<dim3(512),   dim3(256), 0, stream>>>(xz, dtr, bcg, c1w, c1b, dpw, dpb, alog, ablog, dskip, psS, ybuf, flagp);
  k_outln  <<<dim3(1024),  dim3(256), 0, stream>>>(ybuf, xz, opw, lng, lnb, vol_t, flagp);
  // conv #2: vol_t (+skipb) -> d_out, dual-dtype out
  k_convm  <<<dim3(512),   dim3(256), 0, stream>>>(vol_t, wt, conv_b, skipb, nullptr, d_out, 1, flagp);
}

// Round 12
// 455.887 us; speedup vs baseline: 1.2064x; 1.0184x over previous
//
#include <hip/hip_runtime.h>
#include <hip/hip_bf16.h>

typedef __hip_bfloat16 bf16;
typedef __attribute__((ext_vector_type(8))) short short8;   // 8 bf16 = 4 VGPRs
typedef __attribute__((ext_vector_type(4))) float f32x4;    // MFMA acc

__device__ __forceinline__ float b2f(bf16 x){ return __bfloat162float(x); }
__device__ __forceinline__ bf16  f2b(float x){ return __float2bfloat16(x); }
__device__ __forceinline__ float s2f(short s){ bf16 t = *(bf16*)&s; return b2f(t); }

// dual-dtype input load / output store (flag: 1 = fp32 storage, 0 = bf16)
__device__ __forceinline__ float ldin(const void* p, size_t i, int f32){
  return f32 ? ((const float*)p)[i] : b2f(((const bf16*)p)[i]);
}
__device__ __forceinline__ void stout(void* p, size_t i, float v, int f32){
  if(f32) ((float*)p)[i] = v; else ((bf16*)p)[i] = f2b(v);
}

constexpr int SP   = 32*32*32;   // 32768 spatial per (b,c)
constexpr int LTOK = SP;         // tokens per batch
constexpr int NC   = 512;        // scan chunks
constexpr int CLEN = LTOK / NC;  // 64
constexpr int NSEQ = 2*2*64*8;   // 2048 scan sequences (dir,b,d,n)
constexpr int SEG  = 16;         // scan2 hierarchy: 16 segments x 32 chunks
constexpr int SEGLEN = NC/SEG;   // 32

// ---------------------------------------------------------------- dtype detector
__global__ void k_detect(const void* conv_w, int* flag){
  if(threadIdx.x==0 && blockIdx.x==0){
    const bf16* p = (const bf16*)conv_w;
    int f = 0;
    for(int i=0;i<128;i++){
      float v = b2f(p[i]);
      if(!(v==v) || fabsf(v) > 1.0f) f = 1;   // bf16 weights are 0.05-scale
    }
    *flag = f;
  }
}

// ---------------------------------------------------------------- diagnostic fill
__global__ void k_fill(void* out, int n, const int* flag){
  const int f32 = *flag;
  int i = blockIdx.x*256 + threadIdx.x;
  if(i<n) stout(out, i, 12345.0f, f32);
}

// ---------------------------------------------------------------- weight re-layout: wt[tap][oc][ci]
__global__ void k_wprep(const void* __restrict__ cw, bf16* __restrict__ wt,
                        const int* __restrict__ flag){
  const int f32 = *flag;
  int t = blockIdx.x*256 + threadIdx.x;   // 110592 = 27*64*64
  if(t >= 27*64*64) return;
  int tap = t >> 12;          // /4096
  int oc  = (t >> 6) & 63;
  int ci  = t & 63;
  wt[t] = f2b(ldin(cw, ((size_t)(oc*64+ci))*27 + tap, f32));
}

// ---------------------------------------------------------------- in_proj as MFMA GEMM
__global__ __launch_bounds__(256) void k_inprojm(
    const void* __restrict__ in, const void* __restrict__ pw,
    bf16* __restrict__ xz, bf16* __restrict__ xin_t,
    const int* __restrict__ flag){
  const int f32 = *flag;
  __shared__ bf16 tok[128*72];   // [token][c], pitch 72
  __shared__ bf16 wl [128*72];   // [j][c],     pitch 72
  int tid = threadIdx.x;
  int b = blockIdx.x >> 8, tile = blockIdx.x & 255;
  int l0 = tile*128;

  for(int p=tid; p<1024; p+=256){          // weights: (j, c8)
    int j = p & 127, c8 = p >> 7;
    short8 v;
    #pragma unroll
    for(int k=0;k<8;k++){
      bf16 t = f2b(ldin(pw, j*64 + c8*8 + k, f32));
      v[k] = *(short*)&t;
    }
    *(short8*)(&wl[j*72 + c8*8]) = v;
  }
  for(int p=tid; p<1024; p+=256){          // tokens: (i, c8), coalesced over i
    int i = p & 127, c8 = p >> 7;
    short8 v;
    #pragma unroll
    for(int k=0;k<8;k++){
      bf16 t = f2b(ldin(in, ((size_t)(b*64 + c8*8 + k))*SP + l0 + i, f32));
      v[k] = *(short*)&t;
    }
    *(short8*)(&tok[i*72 + c8*8]) = v;
  }
  __syncthreads();

  int lane = tid & 63, wv = tid >> 6;
  int pn = lane & 15, quad = lane >> 4, kg8 = quad*8;
  f32x4 acc[2][8];
  #pragma unroll
  for(int mt=0;mt<2;mt++)
    #pragma unroll
    for(int nt=0;nt<8;nt++) acc[mt][nt]=(f32x4)(0.f);

  #pragma unroll
  for(int kq=0;kq<2;kq++){
    short8 a0 = *(const short8*)(&tok[(wv*32      + pn)*72 + kq*32 + kg8]);
    short8 a1 = *(const short8*)(&tok[(wv*32 + 16 + pn)*72 + kq*32 + kg8]);
    #pragma unroll
    for(int nt=0;nt<8;nt++){
      short8 bb = *(const short8*)(&wl[(nt*16+pn)*72 + kq*32 + kg8]);
      acc[0][nt] = __builtin_amdgcn_mfma_f32_16x16x32_bf16(a0,bb,acc[0][nt],0,0,0);
      acc[1][nt] = __builtin_amdgcn_mfma_f32_16x16x32_bf16(a1,bb,acc[1][nt],0,0,0);
    }
  }

  #pragma unroll
  for(int mt=0;mt<2;mt++){
    #pragma unroll
    for(int nt=0;nt<8;nt++){
      #pragma unroll
      for(int r=0;r<4;r++){
        int token = wv*32 + mt*16 + quad*4 + r;
        xz[((size_t)b*LTOK + l0 + token)*128 + nt*16 + pn] = f2b(acc[mt][nt][r]);
      }
    }
  }
  for(int p=tid; p<8192; p+=256){
    int i = p >> 6, c = p & 63;
    xin_t[((size_t)b*SP + l0 + i)*64 + c] = tok[i*72 + c];
  }
}

// ---------------------------------------------------------------- MFMA conv3d (both convs)
// R12: weights-in-registers. Block = (b, h, w-half, ocg16): 512 pos x 16 oc.
// Per cic-chunk: 27 A-frags hoisted to 108 VGPRs (one batch of global loads),
// then a barrier-free tap loop of pure ds_read_b128 + MFMA on 8 indep accs.
// x-tile 3h x 18w x 34d x 32ci, pitch 36 (132 KB LDS, 1 block/CU).
__global__ __launch_bounds__(256, 1) void k_convm(
    const bf16* __restrict__ xin_t, const bf16* __restrict__ wt,
    const void* __restrict__ cb, const bf16* __restrict__ skip,
    bf16* __restrict__ out_bf, void* __restrict__ out_any,
    int mode, const int* __restrict__ flag){
  const int f32 = *flag;
  __shared__ bf16 xt[1836*36];  // [(hh*18+ww)*34+dd][36] = 132,192 B

  int tid  = threadIdx.x;
  int lane = tid & 63;
  int wv   = tid >> 6;
  int pn   = lane & 15;
  int quad = lane >> 4;
  int kg8  = quad * 8;
  int laneA = pn*64 + kg8;

  int blk = blockIdx.x;         // 512 = 2b * 32h * 2wh * 4ocg
  int ocg = blk & 3;
  int wh  = (blk >> 2) & 1;
  int h   = (blk >> 3) & 31;
  int b   = blk >> 8;
  int w0  = wh*16;

  f32x4 acc[8];                 // [wr][dh]
  #pragma unroll
  for(int m=0;m<8;m++) acc[m]=(f32x4)(0.f);

  for(int cic=0; cic<64; cic+=32){
    if(cic) __syncthreads();
    // stage 3h x 18w x 34d x 32ci (halo rows zero-filled; every row written)
    for(int it=0; it<29; it++){
      int j = it*256 + tid;
      if(j < 7344){
        int q4 = j & 3, row = j >> 2;         // row in [0,1836)
        int hh = row / 612; int rem = row - hh*612;
        int ww = rem / 34;  int dd = rem - ww*34;
        int hg = h + hh - 1, wg = w0 + ww - 1, d = dd - 1;
        short8 v = (short8)(0);
        if((unsigned)hg < 32u && (unsigned)wg < 32u && (unsigned)d < 32u)
          v = *(const short8*)(&xin_t[(((size_t)b*SP) + hg*1024 + wg*32 + d)*64 + cic + q4*8]);
        *(short8*)(&xt[row*36 + q4*8]) = v;
      }
    }
    __syncthreads();

    // hoist all 27 taps' A-frags for this ocg+chunk into registers
    short8 afr[27];
    #pragma unroll
    for(int t=0;t<27;t++)
      afr[t] = *(const short8*)(wt + t*4096 + ocg*1024 + cic + laneA);

    #pragma unroll
    for(int kz=0;kz<3;kz++){
      #pragma unroll
      for(int ky=0;ky<3;ky++){
        #pragma unroll
        for(int kx=0;kx<3;kx++){
          int tap = (kz*3+ky)*3+kx;
          #pragma unroll
          for(int wr=0;wr<4;wr++){
            int rowb = (kz*18 + wv*4 + wr + ky)*34 + kx;
            #pragma unroll
            for(int dh=0;dh<2;dh++){
              int rix = rowb + dh*16 + pn;
              short8 bb = *(const short8*)(&xt[rix*36 + kg8]);
              acc[wr*2+dh] = __builtin_amdgcn_mfma_f32_16x16x32_bf16(afr[tap], bb, acc[wr*2+dh], 0,0,0);
            }
          }
        }
      }
    }
  }

  #pragma unroll
  for(int wr=0;wr<4;wr++){
    #pragma unroll
    for(int dh=0;dh<2;dh++){
      #pragma unroll
      for(int r=0;r<4;r++){
        int oc = ocg*16 + quad*4 + r;
        size_t idx = ((size_t)(b*64+oc))*SP + h*1024 + (w0 + wv*4 + wr)*32 + dh*16 + pn;
        float v = acc[wr*2+dh][r] + ldin(cb, oc, f32);
        if(mode==0) out_bf[idx] = f2b(v);
        else        stout(out_any, idx, v + b2f(skip[idx]), f32);
      }
    }
  }
}

// ---------------------------------------------------------------- instance norm + relu (in place, bf16)
__global__ void k_inorm(bf16* __restrict__ buf){
  int bc = blockIdx.x;
  bf16* p = buf + (size_t)bc*SP;
  float s=0.f, s2=0.f;
  for(int i=threadIdx.x;i<SP;i+=256){ float v=b2f(p[i]); s+=v; s2+=v*v; }
  __shared__ float sh[8];
  #pragma unroll
  for(int m=32;m>=1;m>>=1){ s += __shfl_xor(s,m); s2 += __shfl_xor(s2,m); }
  int wid = threadIdx.x>>6;
  if((threadIdx.x&63)==0){ sh[wid]=s; sh[4+wid]=s2; }
  __syncthreads();
  if(threadIdx.x==0){ float a=0,b2=0; for(int i=0;i<4;i++){a+=sh[i]; b2+=sh[4+i];} sh[0]=a; sh[4]=b2; }
  __syncthreads();
  float mean = sh[0]*(1.f/SP);
  float var  = sh[4]*(1.f/SP) - mean*mean;
  float inv = rsqrtf(fmaxf(var,0.f) + 1e-5f);
  for(int i=threadIdx.x;i<SP;i+=256){
    float v=(b2f(p[i])-mean)*inv;
    p[i] = f2b(v>0.f ? v : 0.f);
  }
}

// ---------------------------------------------------------------- per-direction prep: conv1d+silu, x_proj
__global__ void k_dirprep(const bf16* __restrict__ xz, const void* __restrict__ c1w,
                          const void* __restrict__ c1b, const void* __restrict__ xpw,
                          bf16* __restrict__ bcg, float* __restrict__ dtr,
                          const int* __restrict__ flag){
  const int f32 = *flag;
  __shared__ float xs[67][64];
  __shared__ float xcs[64][65];
  __shared__ float xws[20][65];
  int bid = blockIdx.x;
  int g = bid >> 10, b = (bid>>9)&1, tile = bid & 511;
  int l0 = tile*64;
  int gb = g*2+b;
  for(int t=threadIdx.x; t<20*64; t+=256){ int j=t>>6, d=t&63; xws[j][d]=ldin(xpw, t, f32); }
  for(int t=threadIdx.x; t<67*64; t+=256){
    int row=t>>6, d=t&63;
    int l = l0 + row - 3;
    float v = 0.f;
    if(l>=0 && l<LTOK){
      int lg = g ? (LTOK-1-l) : l;
      v = b2f(xz[((size_t)b*LTOK + lg)*128 + d]);
    }
    xs[row][d]=v;
  }
  __syncthreads();
  for(int t=threadIdx.x; t<4096; t+=256){
    int d=t&63, tl=t>>6;
    float acc = ldin(c1b, d, f32);
    #pragma unroll
    for(int k=0;k<4;k++) acc += ldin(c1w, d*4+k, f32) * xs[tl+k][d];
    xcs[tl][d] = acc / (1.f + __expf(-acc));
  }
  __syncthreads();
  for(int task=threadIdx.x; task<1280; task+=256){
    int j = task % 20, tl = task / 20;
    float acc=0.f;
    #pragma unroll
    for(int d=0; d<64; d++) acc += xcs[tl][d]*xws[j][d];
    size_t l = (size_t)gb*LTOK + l0 + tl;
    if(j<4) dtr[l*4 + j] = acc;
    else    bcg[l*16 + (j-4)] = f2b(acc);
  }
}

// ---------------------------------------------------------------- scan pass1: batched prefetch
__global__ __launch_bounds__(256, 2) void k_scan1(
                        const bf16* __restrict__ xz, const float* __restrict__ dtr,
                        const bf16* __restrict__ bcg,
                        const void* __restrict__ c1w, const void* __restrict__ c1b,
                        const void* __restrict__ dpw, const void* __restrict__ dpb,
                        const void* __restrict__ alog, const void* __restrict__ ablog,
                        float* __restrict__ psP, float* __restrict__ psS,
                        const int* __restrict__ flag){
  const int f32 = *flag;
  int wid = blockIdx.x*4 + (threadIdx.x>>6);
  int lane = threadIdx.x & 63;
  int chunk = wid & (NC-1);
  int b = (wid>>9)&1;
  int g = wid>>10;
  int gb = g*2+b;
  const void* al = g ? ablog : alog;
  float ac[8];
  #pragma unroll
  for(int n=0;n<8;n++) ac[n] = -__expf(ldin(al, lane*8+n, f32));
  float cw0=ldin(c1w,lane*4+0,f32), cw1=ldin(c1w,lane*4+1,f32), cw2=ldin(c1w,lane*4+2,f32), cw3=ldin(c1w,lane*4+3,f32);
  float cb_=ldin(c1b,lane,f32);
  float dw0=ldin(dpw,lane*4+0,f32), dw1=ldin(dpw,lane*4+1,f32), dw2=ldin(dpw,lane*4+2,f32), dw3=ldin(dpw,lane*4+3,f32);
  float db_=ldin(dpb,lane,f32);
  float S[8];
  #pragma unroll
  for(int n=0;n<8;n++) S[n]=0.f;
  float Tsum = 0.f;
  int lt0 = chunk*CLEN;
  float x0,x1,x2;
  {
    float xr[3];
    #pragma unroll
    for(int j=0;j<3;j++){
      int lt = lt0-3+j;
      float v=0.f;
      if(lt>=0){ int lg = g ? (LTOK-1-lt) : lt; v=b2f(xz[((size_t)b*LTOK+lg)*128 + lane]); }
      xr[j]=v;
    }
    x0=xr[0]; x1=xr[1]; x2=xr[2];
  }
  for(int i0=0;i0<CLEN;i0+=8){
    bf16 xv[8]; float4 dv[8]; short8 bb[8];
    #pragma unroll
    for(int k=0;k<8;k++){
      int lt = lt0+i0+k;
      int lg = g ? (LTOK-1-lt) : lt;
      xv[k] = xz[((size_t)b*LTOK+lg)*128 + lane];
      size_t l = (size_t)gb*LTOK + lt;
      dv[k] = *(const float4*)(dtr + l*4);
      bb[k] = *(const short8*)(bcg + l*16);
    }
    #pragma unroll
    for(int k=0;k<8;k++){
      float x3 = b2f(xv[k]);
      float pre = cb_ + cw0*x0 + cw1*x1 + cw2*x2 + cw3*x3;
      float xc = pre / (1.f + __expf(-pre));
      float v = db_ + dv[k].x*dw0 + dv[k].y*dw1 + dv[k].z*dw2 + dv[k].w*dw3;
      float e = __expf(-fabsf(v));
      float dt = fmaxf(v,0.f) + __logf(1.f+e);
      Tsum += dt;
      float bx = dt*xc;
      #pragma unroll
      for(int n=0;n<8;n++){
        float a = __expf(dt*ac[n]);
        S[n] = a*S[n] + bx*s2f(bb[k][n]);
      }
      x0=x1; x1=x2; x2=x3;
    }
  }
  int seq = (gb*64 + lane)*8;
  #pragma unroll
  for(int n=0;n<8;n++){
    psP[(size_t)chunk*NSEQ + seq + n] = __expf(ac[n]*Tsum);
    psS[(size_t)chunk*NSEQ + seq + n] = S[n];
  }
}

// ---------------------------------------------------------------- scan pass2: hierarchical (depth 512 -> 32/16/32)
__global__ void k_scan2a(const float* __restrict__ psP, const float* __restrict__ psS,
                         float* __restrict__ segP, float* __restrict__ segS){
  int idx = blockIdx.x*256 + threadIdx.x;       // 32768 = NSEQ*SEG
  int seq = idx & (NSEQ-1);
  int seg = idx >> 11;
  float P = 1.f, S = 0.f;
  int i0 = seg*SEGLEN;
  #pragma unroll 4
  for(int i=0;i<SEGLEN;i++){
    float p = psP[(size_t)(i0+i)*NSEQ + seq];
    float s = psS[(size_t)(i0+i)*NSEQ + seq];
    S = p*S + s;
    P *= p;
  }
  segP[seg*NSEQ + seq] = P;
  segS[seg*NSEQ + seq] = S;
}
__global__ void k_scan2b(const float* __restrict__ segP, const float* __restrict__ segS,
                         float* __restrict__ segC){
  int seq = blockIdx.x*256 + threadIdx.x;
  if(seq >= NSEQ) return;
  float h = 0.f;
  #pragma unroll
  for(int s=0;s<SEG;s++){
    segC[s*NSEQ + seq] = h;
    h = segP[s*NSEQ + seq]*h + segS[s*NSEQ + seq];
  }
}
__global__ void k_scan2c(const float* __restrict__ psP, const float* __restrict__ segC,
                         float* __restrict__ psC){
  int idx = blockIdx.x*256 + threadIdx.x;
  int seq = idx & (NSEQ-1);
  int seg = idx >> 11;
  float h = segC[seg*NSEQ + seq];
  int i0 = seg*SEGLEN;
  #pragma unroll 4
  for(int i=0;i<SEGLEN;i++){
    float p = psP[(size_t)(i0+i)*NSEQ + seq];
    float s = psC[(size_t)(i0+i)*NSEQ + seq];   // read partial BEFORE overwrite
    psC[(size_t)(i0+i)*NSEQ + seq] = h;
    h = p*h + s;
  }
}

// ---------------------------------------------------------------- scan pass3: batched prefetch, y pre-silu(z)
__global__ __launch_bounds__(256, 2) void k_scan3(
                        const bf16* __restrict__ xz, const float* __restrict__ dtr,
                        const bf16* __restrict__ bcg,
                        const void* __restrict__ c1w, const void* __restrict__ c1b,
                        const void* __restrict__ dpw, const void* __restrict__ dpb,
                        const void* __restrict__ alog, const void* __restrict__ ablog,
                        const void* __restrict__ dskip, const float* __restrict__ carry,
                        bf16* __restrict__ ybuf, const int* __restrict__ flag){
  const int f32 = *flag;
  int wid = blockIdx.x*4 + (threadIdx.x>>6);
  int lane = threadIdx.x & 63;
  int chunk = wid & (NC-1);
  int b = (wid>>9)&1;
  int g = wid>>10;
  int gb = g*2+b;
  const void* al = g ? ablog : alog;
  float ac[8];
  #pragma unroll
  for(int n=0;n<8;n++) ac[n] = -__expf(ldin(al, lane*8+n, f32));
  float cw0=ldin(c1w,lane*4+0,f32), cw1=ldin(c1w,lane*4+1,f32), cw2=ldin(c1w,lane*4+2,f32), cw3=ldin(c1w,lane*4+3,f32);
  float cb_=ldin(c1b,lane,f32);
  float dw0=ldin(dpw,lane*4+0,f32), dw1=ldin(dpw,lane*4+1,f32), dw2=ldin(dpw,lane*4+2,f32), dw3=ldin(dpw,lane*4+3,f32);
  float db_=ldin(dpb,lane,f32);
  float dsk = ldin(dskip,lane,f32);
  int seq = (gb*64 + lane)*8;
  float h[8];
  #pragma unroll
  for(int n=0;n<8;n++) h[n] = carry[(size_t)chunk*NSEQ + seq + n];
  int lt0 = chunk*CLEN;
  float x0,x1,x2;
  {
    float xr[3];
    #pragma unroll
    for(int j=0;j<3;j++){
      int lt = lt0-3+j;
      float v=0.f;
      if(lt>=0){ int lg = g ? (LTOK-1-lt) : lt; v=b2f(xz[((size_t)b*LTOK+lg)*128 + lane]); }
      xr[j]=v;
    }
    x0=xr[0]; x1=xr[1]; x2=xr[2];
  }
  for(int i0=0;i0<CLEN;i0+=8){
    bf16 xv[8]; float4 dv[8]; short8 bb[8]; short8 cc[8];
    #pragma unroll
    for(int k=0;k<8;k++){
      int lt = lt0+i0+k;
      int lg = g ? (LTOK-1-lt) : lt;
      xv[k] = xz[((size_t)b*LTOK+lg)*128 + lane];
      size_t l = (size_t)gb*LTOK + lt;
      dv[k] = *(const float4*)(dtr + l*4);
      bb[k] = *(const short8*)(bcg + l*16);
      cc[k] = *(const short8*)(bcg + l*16 + 8);
    }
    #pragma unroll
    for(int k=0;k<8;k++){
      float x3 = b2f(xv[k]);
      float pre = cb_ + cw0*x0 + cw1*x1 + cw2*x2 + cw3*x3;
      float xc = pre / (1.f + __expf(-pre));
      float v = db_ + dv[k].x*dw0 + dv[k].y*dw1 + dv[k].z*dw2 + dv[k].w*dw3;
      float e = __expf(-fabsf(v));
      float dt = fmaxf(v,0.f) + __logf(1.f+e);
      float bx = dt*xc;
      float y = xc*dsk;
      #pragma unroll
      for(int n=0;n<8;n++){
        float a = __expf(dt*ac[n]);
        h[n] = a*h[n] + bx*s2f(bb[k][n]);
        y += h[n]*s2f(cc[k][n]);
      }
      size_t l = (size_t)gb*LTOK + lt0+i0+k;
      ybuf[l*64 + lane] = f2b(y);
      x0=x1; x1=x2; x2=x3;
    }
  }
}

// ---------------------------------------------------------------- combine dirs * silu(z) + out_proj (MFMA) + LN -> vol (token-major)
__global__ __launch_bounds__(256) void k_outln(
                        const bf16* __restrict__ ybuf, const bf16* __restrict__ xz,
                        const void* __restrict__ opw,
                        const void* __restrict__ lng, const void* __restrict__ lnb,
                        bf16* __restrict__ vol_t, const int* __restrict__ flag){
  const int f32 = *flag;
  __shared__ bf16 vsm[64*72];   // [token][d] pitch 72; reused for LN output staging
  __shared__ bf16 wsm[64*72];   // [c][d]     pitch 72
  __shared__ float gsm[64], bsm[64];
  int tid = threadIdx.x;
  int b = blockIdx.x >> 9, tile = blockIdx.x & 511;
  int l0 = tile*64;

  for(int p=tid; p<512; p+=256){           // weights (c, d8)
    int c = p & 63, d8 = p >> 6;
    short8 v;
    #pragma unroll
    for(int k=0;k<8;k++){ bf16 t = f2b(ldin(opw, c*64 + d8*8 + k, f32)); v[k] = *(short*)&t; }
    *(short8*)(&wsm[c*72 + d8*8]) = v;
  }
  if(tid<64){ gsm[tid]=ldin(lng,tid,f32); bsm[tid]=ldin(lnb,tid,f32); }
  for(int p=tid; p<4096; p+=256){          // v = 0.5(yf+yb)*silu(z)
    int tl = p >> 6, d = p & 63;
    int l = l0 + tl;
    float yf = b2f(ybuf[((size_t)(0+b)*LTOK + l)*64 + d]);
    float yb = b2f(ybuf[((size_t)(2+b)*LTOK + (LTOK-1-l))*64 + d]);
    float z  = b2f(xz[((size_t)b*LTOK + l)*128 + 64 + d]);
    float sz = z / (1.f + __expf(-z));
    vsm[tl*72 + d] = f2b(0.5f*(yf+yb)*sz);
  }
  __syncthreads();

  int lane = tid & 63, wv = tid >> 6, pn = lane & 15, quad = lane >> 4, kg8 = quad*8;
  f32x4 acc[4];
  #pragma unroll
  for(int nt=0;nt<4;nt++) acc[nt]=(f32x4)(0.f);
  #pragma unroll
  for(int kq=0;kq<2;kq++){
    short8 a = *(const short8*)(&vsm[(wv*16+pn)*72 + kq*32 + kg8]);
    #pragma unroll
    for(int nt=0;nt<4;nt++){
      short8 bb = *(const short8*)(&wsm[(nt*16+pn)*72 + kq*32 + kg8]);
      acc[nt] = __builtin_amdgcn_mfma_f32_16x16x32_bf16(a,bb,acc[nt],0,0,0);
    }
  }
  __syncthreads();   // all reads of vsm done; safe to overwrite below

  float gl[4], bl[4];
  #pragma unroll
  for(int nt=0;nt<4;nt++){ gl[nt]=gsm[nt*16+pn]; bl[nt]=bsm[nt*16+pn]; }
  #pragma unroll
  for(int r=0;r<4;r++){
    float vals[4]; float s=0.f;
    #pragma unroll
    for(int nt=0;nt<4;nt++){ vals[nt]=acc[nt][r]; s+=vals[nt]; }
    #pragma unroll
    for(int m=1;m<16;m<<=1) s += __shfl_xor(s, m);
    float mu = s*(1.f/64.f);
    float s2=0.f;
    #pragma unroll
    for(int nt=0;nt<4;nt++){ float dv=vals[nt]-mu; s2+=dv*dv; }
    #pragma unroll
    for(int m=1;m<16;m<<=1) s2 += __shfl_xor(s2, m);
    float inv = rsqrtf(s2*(1.f/64.f) + 1e-5f);
    int token = wv*16 + quad*4 + r;
    #pragma unroll
    for(int nt=0;nt<4;nt++){
      vsm[token*72 + nt*16 + pn] = f2b((vals[nt]-mu)*inv*gl[nt] + bl[nt]);
    }
  }
  __syncthreads();
  for(int p=tid; p<512; p+=256){           // coalesced token-major short8 stores
    int tl = p >> 3, d8 = p & 7;
    *(short8*)(&vol_t[((size_t)b*SP + l0 + tl)*64 + d8*8]) = *(const short8*)(&vsm[tl*72 + d8*8]);
  }
}

// ---------------------------------------------------------------- launch
extern "C" void kernel_launch(void* const* d_in, const int* in_sizes, int n_in,
                              void* d_out, int out_size, void* d_ws, size_t ws_size,
                              hipStream_t stream){
  const void* input  = d_in[0];
  const void* conv_w = d_in[1];
  const void* conv_b = d_in[2];
  const void* inpw   = d_in[3];
  const void* c1w    = d_in[4];
  const void* c1b    = d_in[5];
  const void* xpw    = d_in[6];
  const void* dpw    = d_in[7];
  const void* dpb    = d_in[8];
  const void* alog   = d_in[9];
  const void* ablog  = d_in[10];
  const void* dskip  = d_in[11];
  const void* opw    = d_in[12];
  const void* lng    = d_in[13];
  const void* lnb    = d_in[14];

  char* base = (char*)d_ws;
  bf16*  skipb = (bf16*) (base + 0);            //  8,388,608 B
  bf16*  xz    = (bf16*) (base + 8388608);      // 16,777,216 B
  bf16*  bcg   = (bf16*) (base + 25165824);     //  4,194,304 B
  float* dtr   = (float*)(base + 29360128);     //  2,097,152 B
  float* psP   = (float*)(base + 31457280);     //  4,194,304 B
  float* psS   = (float*)(base + 35651584);     //  4,194,304 B (reused in-place as carry)
  bf16*  ybuf  = (bf16*) (base + 39845888);     // 16,777,216 B
  bf16*  wt    = (bf16*) (base + 56623104);     //    221,184 B (ends 56,844,288)
  float* segP  = (float*)(base + 56844288);     //    131,072 B
  float* segS  = (float*)(base + 56975360);     //    131,072 B
  float* segC  = (float*)(base + 57106432);     //    131,072 B (ends 57,237,504)
  bf16*  xin_t = (bf16*) (base + 31457280);     //  8,388,608 B alias psP+psS (dead until scan1)
  bf16*  vol_t = (bf16*) (base + 25165824);     //  8,388,608 B alias bcg+dtr+psP[0:2.1M] (dead after scan2/scan3)
  int*   flagp = (int*)  (base + 60817408);     //  16 B
  const size_t NEED = 60817424;

  k_detect<<<dim3(1), dim3(64), 0, stream>>>(conv_w, flagp);

  if(ws_size < NEED){
    k_fill<<<dim3((out_size+255)/256), dim3(256), 0, stream>>>(d_out, out_size, flagp);
    return;
  }

  k_wprep  <<<dim3(432),   dim3(256), 0, stream>>>(conv_w, wt, flagp);
  k_inprojm<<<dim3(512),   dim3(256), 0, stream>>>(input, inpw, xz, xin_t, flagp);
  // conv #1: xin_t -> skipb (bf16, channel-major out)
  k_convm  <<<dim3(512),   dim3(256), 0, stream>>>(xin_t, wt, conv_b, nullptr, skipb, nullptr, 0, flagp);
  k_inorm  <<<dim3(128),   dim3(256), 0, stream>>>(skipb);
  k_dirprep<<<dim3(2048),  dim3(256), 0, stream>>>(xz, c1w, c1b, xpw, bcg, dtr, flagp);
  k_scan1  <<<dim3(512),   dim3(256), 0, stream>>>(xz, dtr, bcg, c1w, c1b, dpw, dpb, alog, ablog, psP, psS, flagp);
  k_scan2a <<<dim3(128),   dim3(256), 0, stream>>>(psP, psS, segP, segS);
  k_scan2b <<<dim3(8),     dim3(256), 0, stream>>>(segP, segS, segC);
  k_scan2c <<<dim3(128),   dim3(256), 0, stream>>>(psP, segC, psS);
  k_scan3  <<<dim3(512),   dim3(256), 0, stream>>>(xz, dtr, bcg, c1w, c1b, dpw, dpb, alog, ablog, dskip, psS, ybuf, flagp);
  k_outln  <<<dim3(1024),  dim3(256), 0, stream>>>(ybuf, xz, opw, lng, lnb, vol_t, flagp);
  // conv #2: vol_t (+skipb) -> d_out, dual-dtype out
  k_convm  <<<dim3(512),   dim3(256), 0, stream>>>(vol_t, wt, conv_b, skipb, nullptr, d_out, 1, flagp);
}